// Round 15
// baseline (152.674 us; speedup 1.0000x reference)
//
#include <hip/hip_runtime.h>

#define BATCH 8
#define CHN 128
#define HH 160
#define WW 160
#define HW (HH*WW)
#define RR 2
#define MAXOFF 5
#define NOFF 25
#define TW 32
#define TH 8
#define NG 4               /* channel groups = waves per block */
#define CPG (CHN/NG)       /* 32 channels per group */
#define RC 2               /* channels per group per round */
#define ROUNDS (CPG/RC)    /* 16 */
#define NTHREADS 256
#define NPT 64             /* lanes per wave */
#define OCH 4              /* epilogue chunk */
#define EPFL (2*(NG-1)*OCH*NPT*2)   /* 3072 floats = 12288 B */

__device__ __forceinline__ int reflect_idx(int i, int n) {
    if (i < 0) i = -i;
    if (i >= n) i = 2 * (n - 1) - i;
    return i;
}

__global__ __launch_bounds__(NTHREADS) void costvol_kernel(
    const float* __restrict__ c1,
    const float* __restrict__ c2,
    const float* __restrict__ pw,
    float* __restrict__ out)
{
    __shared__ float lds[EPFL];        // epilogue exchange only

    const int tid  = threadIdx.x;
    const int g    = tid >> 6;         // wave = channel group 0..3
    const int lane = tid & 63;
    const int xh   = lane & 15;        // float2 column 0..15
    const int yg   = lane >> 4;        // row-pair 0..3 -> rows 2yg, 2yg+1

    // XCD-aware swizzle: 800 = 8 XCDs x 100 tiles; XCD k owns batch image k.
    int bidx = (int)blockIdx.x;
    bidx = (bidx & 7) * 100 + (bidx >> 3);
    const int tx0 = (bidx % (WW / TW)) * TW; bidx /= (WW / TW);
    const int ty0 = (bidx % (HH / TH)) * TH; bidx /= (HH / TH);
    const int b = bidx;

    const bool Ledge = (tx0 == 0);
    const bool Redge = (tx0 == WW - TW);

    // ---- round-invariant window byte offsets: 6 rows x 3 col-slots ----
    // off[dr*3+i] = reflect-row byte offset + clamped col byte offset.
    int off[18];
#pragma unroll
    for (int dr = 0; dr < 6; ++dr) {
        const int gr = reflect_idx(ty0 + 2 * yg - RR + dr, HH);
        const int rb = gr * WW * 4;
#pragma unroll
        for (int i = 0; i < 3; ++i) {
            int cs = tx0 + 2 * xh - RR + 2 * i;           // float2 start col
            cs = (cs < 0) ? 0 : ((cs > WW - 2) ? WW - 2 : cs);
            off[dr * 3 + i] = rb + cs * 4;
        }
    }

    const char*  c2g = (const char*)(c2 + ((size_t)b * CHN + g * CPG) * HW);
    const float* c1p = c1 + ((size_t)b * CHN + g * CPG) * HW
                          + (ty0 + 2 * yg) * WW + tx0 + xh * 2;

    float2 acc0[NOFF], acc1[NOFF];     // 100 VGPRs
#pragma unroll
    for (int i = 0; i < NOFF; ++i) {
        acc0[i] = make_float2(0.f, 0.f);
        acc1[i] = make_float2(0.f, 0.f);
    }

    for (int r = 0; r < ROUNDS; ++r) {
        // c1 values for this round: 2 channels x 2 rows
        float2 s0[RC], s1[RC];
#pragma unroll
        for (int j = 0; j < RC; ++j) {
            s0[j] = *(const float2*)(c1p + (size_t)(r * RC + j) * HW);
            s1[j] = *(const float2*)(c1p + (size_t)(r * RC + j) * HW + WW);
        }
#pragma unroll
        for (int j = 0; j < RC; ++j) {
            const char* chb = c2g + (size_t)(r * RC + j) * HW * 4;
            const float2 a0 = s0[j];
            const float2 a1 = s1[j];
#pragma unroll
            for (int dr = 0; dr < 6; ++dr) {
                float2 w0 = *(const float2*)(chb + off[dr * 3 + 0]);
                float2 w1 = *(const float2*)(chb + off[dr * 3 + 1]);
                float2 w2 = *(const float2*)(chb + off[dr * 3 + 2]);
                // reflect fixups at the two x-edge block columns (1 elem each):
                // left: cols (-2,-1)->(2,1); clamped read gave (0,1) => fix .x
                if (Ledge) {
                    if (xh == 0)
                        w0.x = *(const float*)(chb + off[dr * 3 + 0] + 8);
                }
                // right: cols (160,161)->(158,157); clamped gave (158,159) => fix .y
                if (Redge) {
                    if (xh == 15)
                        w2.y = *(const float*)(chb + off[dr * 3 + 2] - 4);
                }
                if (dr < 5) {      // window row dr feeds output row 0 at dy=dr
                    float2* A = &acc0[dr * MAXOFF];
                    A[0].x = fmaf(a0.x, w0.x, A[0].x);  A[0].y = fmaf(a0.y, w0.y, A[0].y);
                    A[1].x = fmaf(a0.x, w0.y, A[1].x);  A[1].y = fmaf(a0.y, w1.x, A[1].y);
                    A[2].x = fmaf(a0.x, w1.x, A[2].x);  A[2].y = fmaf(a0.y, w1.y, A[2].y);
                    A[3].x = fmaf(a0.x, w1.y, A[3].x);  A[3].y = fmaf(a0.y, w2.x, A[3].y);
                    A[4].x = fmaf(a0.x, w2.x, A[4].x);  A[4].y = fmaf(a0.y, w2.y, A[4].y);
                }
                if (dr >= 1) {     // window row dr feeds output row 1 at dy=dr-1
                    float2* A = &acc1[(dr - 1) * MAXOFF];
                    A[0].x = fmaf(a1.x, w0.x, A[0].x);  A[0].y = fmaf(a1.y, w0.y, A[0].y);
                    A[1].x = fmaf(a1.x, w0.y, A[1].x);  A[1].y = fmaf(a1.y, w1.x, A[1].y);
                    A[2].x = fmaf(a1.x, w1.x, A[2].x);  A[2].y = fmaf(a1.y, w1.y, A[2].y);
                    A[3].x = fmaf(a1.x, w1.y, A[3].x);  A[3].y = fmaf(a1.y, w2.x, A[3].y);
                    A[4].x = fmaf(a1.x, w2.x, A[4].x);  A[4].y = fmaf(a1.y, w2.y, A[4].y);
                }
            }
        }
    }

    // ---- cross-wave reduction (g1..g3 -> g0) + scale + PReLU + store ----
    const float a = pw[0];
    const float inv_c = 1.0f / (float)CHN;
    float2* e0 = (float2*)lds;                   // 3*OCH*64 fl2 = 6144 B
    float2* e1 = e0 + (NG - 1) * OCH * NPT;      // + 6144 B

    for (int o0 = 0; o0 < NOFF; o0 += OCH) {
        const int K = (NOFF - o0) < OCH ? (NOFF - o0) : OCH;
        if (g > 0) {
#pragma unroll
            for (int k = 0; k < OCH; ++k)
                if (k < K) {
                    e0[((g - 1) * OCH + k) * NPT + lane] = acc0[o0 + k];
                    e1[((g - 1) * OCH + k) * NPT + lane] = acc1[o0 + k];
                }
        }
        __syncthreads();
        if (g == 0) {
#pragma unroll
            for (int k = 0; k < OCH; ++k) {
                if (k < K) {
                    const int o = o0 + k;
                    float2 u = acc0[o];
                    float2 v = acc1[o];
#pragma unroll
                    for (int q = 0; q < NG - 1; ++q) {
                        float2 ua = e0[(q * OCH + k) * NPT + lane];
                        float2 va = e1[(q * OCH + k) * NPT + lane];
                        u.x += ua.x; u.y += ua.y;
                        v.x += va.x; v.y += va.y;
                    }
                    float ux = u.x * inv_c, uy = u.y * inv_c;
                    float vx = v.x * inv_c, vy = v.y * inv_c;
                    ux = (ux >= 0.f) ? ux : a * ux;
                    uy = (uy >= 0.f) ? uy : a * uy;
                    vx = (vx >= 0.f) ? vx : a * vx;
                    vy = (vy >= 0.f) ? vy : a * vy;
                    float* op = out + (size_t)(b * NOFF + o) * HW
                              + (ty0 + 2 * yg) * WW + tx0 + xh * 2;
                    *(float2*)op        = make_float2(ux, uy);
                    *(float2*)(op + WW) = make_float2(vx, vy);
                }
            }
        }
        if (o0 + OCH < NOFF)
            __syncthreads();           // protect e0/e1 before next chunk's writes
    }
}

extern "C" void kernel_launch(void* const* d_in, const int* in_sizes, int n_in,
                              void* d_out, int out_size, void* d_ws, size_t ws_size,
                              hipStream_t stream) {
    const float* c1 = (const float*)d_in[0];
    const float* c2 = (const float*)d_in[1];
    const float* pw = (const float*)d_in[2];
    float* out = (float*)d_out;

    dim3 grid((WW / TW) * (HH / TH) * BATCH);   // 5*20*8 = 800 blocks
    dim3 block(NTHREADS);
    costvol_kernel<<<grid, block, 0, stream>>>(c1, c2, pw, out);
}

// Round 17
// 64.411 us; speedup vs baseline: 2.3703x; 2.3703x over previous
//
#include <hip/hip_runtime.h>

#define BATCH 8
#define CHN 128
#define HH 160
#define WW 160
#define HW (HH*WW)
#define RR 2
#define MAXOFF 5
#define NOFF 25
#define TW 32
#define TH 8
#define PW (TW + 2*RR)     /* 36 */
#define PH (TH + 2*RR)     /* 12 */
#define NG 4               /* channel groups per block */
#define CPG (CHN/NG)       /* 32 channels per group */
#define RC 2               /* channels per group per round */
#define SCH (NG*RC)        /* 8 staged channels per round */
#define ROUNDS (CPG/RC)    /* 16 */
#define NPT 64             /* threads per group: 16 xh x 4 yg (2 rows each) */
#define NTHREADS 256
#define CHFL (PH*PW)       /* 432 floats per staged channel */
#define STFL (SCH*CHFL)    /* 3456 floats staged per round */
#define NSLOT 14           /* ceil(STFL/NTHREADS) */
#define OCH 4              /* epilogue offset chunk */

__device__ __forceinline__ int reflect_idx(int i, int n) {
    if (i < 0) i = -i;
    if (i >= n) i = 2 * (n - 1) - i;
    return i;
}

// DPP row-shift-RIGHT within 16-lane rows: lane i receives lane i-N's value.
// ROW_SHR1 = 0x111, ROW_SHR2 = 0x112. bound_ctrl=true -> lanes with
// (lane&15) < N read 0; those lanes are patched with real LDS loads below.
template<int CTRL>
__device__ __forceinline__ float2 dpp_shr2(float2 v) {
    float2 r;
    r.x = __int_as_float(__builtin_amdgcn_update_dpp(
              0, __float_as_int(v.x), CTRL, 0xf, 0xf, true));
    r.y = __int_as_float(__builtin_amdgcn_update_dpp(
              0, __float_as_int(v.y), CTRL, 0xf, 0xf, true));
    return r;
}

__global__ __launch_bounds__(NTHREADS) void costvol_kernel(
    const float* __restrict__ c1,
    const float* __restrict__ c2,
    const float* __restrict__ pw,
    float* __restrict__ out)
{
    __shared__ float lds[STFL];        // 13824 B

    const int tid = threadIdx.x;
    const int g  = tid >> 6;           // channel group 0..3
    const int pt = tid & (NPT - 1);    // 0..63
    const int xh = pt & 15;            // float2 column 0..15 (DPP row index)
    const int yg = pt >> 4;            // row-pair 0..3 -> rows 2yg, 2yg+1

    // XCD-aware swizzle: 800 = 8 XCDs x 100 tiles; XCD k owns batch image k.
    int bidx = (int)blockIdx.x;
    bidx = (bidx & 7) * 100 + (bidx >> 3);
    const int tx0 = (bidx % (WW / TW)) * TW; bidx /= (WW / TW);
    const int ty0 = (bidx % (HH / TH)) * TH; bidx /= (HH / TH);
    const int b = bidx;

    // ---- round-invariant staging byte offsets ----
    int boff[NSLOT];
#pragma unroll
    for (int k = 0; k < NSLOT; ++k) {
        const int idx = tid + k * NTHREADS;
        if (idx < STFL) {
            int c   = idx / CHFL;          // staged slot 0..7
            int rem = idx - c * CHFL;
            int ty  = rem / PW;
            int tx  = rem - ty * PW;
            int gh  = c >> 1, j = c & 1;   // owner group, channel-within-round
            int gr  = reflect_idx(ty0 - RR + ty, HH);
            int gc  = reflect_idx(tx0 - RR + tx, WW);
            boff[k] = ((gh * CPG + j) * HW + gr * WW + gc) * 4;
        } else {
            boff[k] = 0;
        }
    }

    const char*  c2b = (const char*)(c2 + (size_t)b * CHN * HW);
    const float* c1p = c1 + ((size_t)b * CHN + g * CPG) * HW
                          + (ty0 + 2 * yg) * WW + tx0 + xh * 2;

    float  sv[NSLOT];                  // staged c2 values in flight
    float2 sc0[RC], sc1[RC], sn0[RC], sn1[RC];   // c1 rows 0/1, cur/next

    auto issue_c2 = [&](int r) {
        const char* base = c2b + (size_t)r * RC * HW * 4;
#pragma unroll
        for (int k = 0; k < NSLOT; ++k)
            if (tid + k * NTHREADS < STFL)
                sv[k] = *(const float*)(base + boff[k]);
    };
    auto write_lds = [&]() {
#pragma unroll
        for (int k = 0; k < NSLOT; ++k)
            if (tid + k * NTHREADS < STFL)
                lds[tid + k * NTHREADS] = sv[k];
    };
    auto issue_c1 = [&](int r, float2* d0, float2* d1) {
#pragma unroll
        for (int j = 0; j < RC; ++j) {
            d0[j] = *(const float2*)(c1p + (size_t)(r * RC + j) * HW);
            d1[j] = *(const float2*)(c1p + (size_t)(r * RC + j) * HW + WW);
        }
    };

    float2 acc0[NOFF], acc1[NOFF];     // 100 VGPRs
#pragma unroll
    for (int i = 0; i < NOFF; ++i) {
        acc0[i] = make_float2(0.f, 0.f);
        acc1[i] = make_float2(0.f, 0.f);
    }

    // ---- prologue: stage round 0, prefetch round 1 ----
    issue_c2(0);
    issue_c1(0, sc0, sc1);
    write_lds();
    __syncthreads();                   // lds holds round 0
    issue_c2(1);
    issue_c1(1, sn0, sn1);

    for (int r = 0; r < ROUNDS; ++r) {
        // compute round r: 2 channels x 2 rows x 25 offsets
        const float* lbase = lds + (g * RC) * CHFL + (2 * yg) * PW + xh * 2;
#pragma unroll
        for (int j = 0; j < RC; ++j) {
            const float* tb = lbase + j * CHFL;
            // Load only w2 (cols 2xh+4,2xh+5) per row; derive w1/w0 from the
            // lower-lane neighbors' w2 via DPP row_shr (VALU pipe, not LDS).
            float2 w2r[6], w1r[6], w0r[6];
#pragma unroll
            for (int dr = 0; dr < 6; ++dr)
                w2r[dr] = *(const float2*)(tb + dr * PW + 4);
#pragma unroll
            for (int dr = 0; dr < 6; ++dr) {
                w1r[dr] = dpp_shr2<0x111>(w2r[dr]);   // lane xh-1's w2
                w0r[dr] = dpp_shr2<0x112>(w2r[dr]);   // lane xh-2's w2
            }
            if (xh < 2) {              // edge lanes: patch with real loads
#pragma unroll
                for (int dr = 0; dr < 6; ++dr) {
                    w0r[dr] = *(const float2*)(tb + dr * PW);
                    if (xh == 1)
                        ;              // w1r valid via row_shr:1 from xh==0
                    if (xh == 0)
                        w1r[dr] = *(const float2*)(tb + dr * PW + 2);
                }
            }
            const float2 s0 = sc0[j];
            const float2 s1 = sc1[j];
#pragma unroll
            for (int dy = 0; dy < MAXOFF; ++dy) {
                {   // output row 0 uses window row dy
                    const float2 w0 = w0r[dy], w1 = w1r[dy], w2 = w2r[dy];
                    float2* A = &acc0[dy * MAXOFF];
                    A[0].x = fmaf(s0.x, w0.x, A[0].x);  A[0].y = fmaf(s0.y, w0.y, A[0].y);
                    A[1].x = fmaf(s0.x, w0.y, A[1].x);  A[1].y = fmaf(s0.y, w1.x, A[1].y);
                    A[2].x = fmaf(s0.x, w1.x, A[2].x);  A[2].y = fmaf(s0.y, w1.y, A[2].y);
                    A[3].x = fmaf(s0.x, w1.y, A[3].x);  A[3].y = fmaf(s0.y, w2.x, A[3].y);
                    A[4].x = fmaf(s0.x, w2.x, A[4].x);  A[4].y = fmaf(s0.y, w2.y, A[4].y);
                }
                {   // output row 1 uses window row dy+1
                    const float2 w0 = w0r[dy + 1], w1 = w1r[dy + 1], w2 = w2r[dy + 1];
                    float2* A = &acc1[dy * MAXOFF];
                    A[0].x = fmaf(s1.x, w0.x, A[0].x);  A[0].y = fmaf(s1.y, w0.y, A[0].y);
                    A[1].x = fmaf(s1.x, w0.y, A[1].x);  A[1].y = fmaf(s1.y, w1.x, A[1].y);
                    A[2].x = fmaf(s1.x, w1.x, A[2].x);  A[2].y = fmaf(s1.y, w1.y, A[2].y);
                    A[3].x = fmaf(s1.x, w1.y, A[3].x);  A[3].y = fmaf(s1.y, w2.x, A[3].y);
                    A[4].x = fmaf(s1.x, w2.x, A[4].x);  A[4].y = fmaf(s1.y, w2.y, A[4].y);
                }
            }
        }
        __syncthreads();               // everyone done reading lds (round r)
        if (r + 1 < ROUNDS) {
            write_lds();               // waits on round r+1's loads, writes them
#pragma unroll
            for (int j = 0; j < RC; ++j) {
                sc0[j] = sn0[j];
                sc1[j] = sn1[j];
            }
            __syncthreads();           // lds holds round r+1
            if (r + 2 < ROUNDS) {
                issue_c2(r + 2);
                issue_c1(r + 2, sn0, sn1);
            }
        }
    }

    // ---- cross-group reduction (g1..g3 -> g0) + scale + PReLU + store ----
    const float a = pw[0];
    const float inv_c = 1.0f / (float)CHN;
    // two float2 regions: row0 at [0], row1 at [3*OCH*NPT*2] floats
    float2* e0 = (float2*)lds;                       // 3*OCH*64 float2 = 6144 B
    float2* e1 = (float2*)(lds + 3 * OCH * NPT * 2); // same size, total 12288 B

    for (int o0 = 0; o0 < NOFF; o0 += OCH) {
        const int K = (NOFF - o0) < OCH ? (NOFF - o0) : OCH;
        __syncthreads();
        if (g > 0) {
#pragma unroll
            for (int k = 0; k < OCH; ++k)
                if (k < K) {
                    e0[((g - 1) * OCH + k) * NPT + pt] = acc0[o0 + k];
                    e1[((g - 1) * OCH + k) * NPT + pt] = acc1[o0 + k];
                }
        }
        __syncthreads();
        if (g == 0) {
#pragma unroll
            for (int k = 0; k < OCH; ++k) {
                if (k < K) {
                    const int o = o0 + k;
                    float2 u = acc0[o];
                    float2 v = acc1[o];
#pragma unroll
                    for (int q = 0; q < 3; ++q) {
                        float2 ua = e0[(q * OCH + k) * NPT + pt];
                        float2 va = e1[(q * OCH + k) * NPT + pt];
                        u.x += ua.x; u.y += ua.y;
                        v.x += va.x; v.y += va.y;
                    }
                    float ux = u.x * inv_c, uy = u.y * inv_c;
                    float vx = v.x * inv_c, vy = v.y * inv_c;
                    ux = (ux >= 0.f) ? ux : a * ux;
                    uy = (uy >= 0.f) ? uy : a * uy;
                    vx = (vx >= 0.f) ? vx : a * vx;
                    vy = (vy >= 0.f) ? vy : a * vy;
                    float* op = out + (size_t)(b * NOFF + o) * HW
                              + (ty0 + 2 * yg) * WW + tx0 + xh * 2;
                    *(float2*)op        = make_float2(ux, uy);
                    *(float2*)(op + WW) = make_float2(vx, vy);
                }
            }
        }
    }
}

extern "C" void kernel_launch(void* const* d_in, const int* in_sizes, int n_in,
                              void* d_out, int out_size, void* d_ws, size_t ws_size,
                              hipStream_t stream) {
    const float* c1 = (const float*)d_in[0];
    const float* c2 = (const float*)d_in[1];
    const float* pw = (const float*)d_in[2];
    float* out = (float*)d_out;

    dim3 grid((WW / TW) * (HH / TH) * BATCH);   // 5*20*8 = 800 blocks
    dim3 block(NTHREADS);
    costvol_kernel<<<grid, block, 0, stream>>>(c1, c2, pw, out);
}